// Round 19
// baseline (4830.666 us; speedup 1.0000x reference)
//
#include <hip/hip_runtime.h>
#include <hip/hip_bf16.h>
#include <stdint.h>
#include <math.h>

typedef __attribute__((ext_vector_type(4))) float f32x4;
typedef __attribute__((ext_vector_type(8))) short short8;   // 8 bf16

#define NB 64      // batch
#define NT 63      // time steps (captions[:, :-1])
#define NE 512     // embed dim
#define NH 512     // hidden dim
#define NV 32000   // vocab
#define NG 2048    // 4*H gates

__device__ __forceinline__ float sigm(float x) { return 1.f / (1.f + expf(-x)); }
__device__ __forceinline__ unsigned short f2b(float f) {   // f32 -> bf16 RNE
  union { float f; uint32_t u; } x; x.f = f;
  uint32_t r = x.u + 0x7FFF + ((x.u >> 16) & 1);
  return (unsigned short)(r >> 16);
}
__device__ __forceinline__ float b2f(unsigned short s) {
  union { uint32_t u; float f; } x; x.u = ((uint32_t)s) << 16; return x.f;
}
__device__ __forceinline__ f32x4 mfma16(short8 a, short8 b, f32x4 c) {
  return __builtin_amdgcn_mfma_f32_16x16x32_bf16(a, b, c, 0, 0, 0);
}

// ---- kernel 0a: Wout f32 -> bf16; zero hs pad rows --------------------------
__global__ __launch_bounds__(256) void k_prep(
    const float* __restrict__ Wout, unsigned short* __restrict__ wb,
    unsigned short* __restrict__ hsb) {
  const int n4 = NV * NH / 4;
  for (int i = blockIdx.x * 256 + threadIdx.x; i < n4; i += gridDim.x * 256) {
    f32x4 v = *(const f32x4*)(Wout + (size_t)i * 4);
    unsigned short o[4];
#pragma unroll
    for (int u = 0; u < 4; ++u) o[u] = f2b(v[u]);
    *(uint64_t*)(wb + (size_t)i * 4) = *(const uint64_t*)o;
  }
  for (int i = blockIdx.x * 256 + threadIdx.x; i < 64 * NH; i += gridDim.x * 256)
    hsb[(size_t)(NT * NB) * NH + i] = 0;   // pad rows 4032..4095
}

// ---- kernel 0b: pack W_hh -> bf16, gate-interleaved rows n' = 4*J + G -------
__global__ __launch_bounds__(256) void k_prep2(
    const float* __restrict__ Whh, unsigned short* __restrict__ wp) {
  const int n4 = NG * NH / 4;
  for (int i4 = blockIdx.x * 256 + threadIdx.x; i4 < n4; i4 += gridDim.x * 256) {
    int r = i4 >> 7;                 // original row: G*512 + J
    int k4 = (i4 & 127) * 4;
    int np = 4 * (r & 511) + (r >> 9);
    f32x4 v = *(const f32x4*)(Whh + (size_t)r * NH + k4);
    unsigned short o[4];
#pragma unroll
    for (int u = 0; u < 4; ++u) o[u] = f2b(v[u]);
    *(uint64_t*)(wp + (size_t)np * NH + k4) = *(const uint64_t*)o;
  }
}

// ---- kernel 1: h0 = tanh(enc@Wh^T+bh), c0 = tanh(enc@Wc^T+bc) ---------------
__global__ __launch_bounds__(256) void k_init(
    const float* __restrict__ enc, const float* __restrict__ Wh, const float* __restrict__ bh,
    const float* __restrict__ Wc, const float* __restrict__ bc,
    float* __restrict__ c0, float* __restrict__ h0) {
  int b = blockIdx.x;
  __shared__ float se[NE];
  for (int e = threadIdx.x; e < NE; e += 256) se[e] = enc[b * NE + e];
  __syncthreads();
  for (int j = threadIdx.x; j < NH; j += 256) {
    float dh = 0.f, dc = 0.f;
    const float* wh = Wh + (size_t)j * NE;
    const float* wc = Wc + (size_t)j * NE;
    for (int e = 0; e < NE; e += 4) {
      f32x4 vh = *(const f32x4*)(wh + e);
      f32x4 vc = *(const f32x4*)(wc + e);
#pragma unroll
      for (int u = 0; u < 4; ++u) {
        float x = se[e + u];
        dh += x * vh[u];
        dc += x * vc[u];
      }
    }
    h0[b * NH + j] = tanhf(dh + bh[j]);
    c0[b * NH + j] = tanhf(dc + bc[j]);
  }
}

// ---- kernel 2 (f32): xp[t][b][4*J+G] = emb(cap[b][t]) . W_ih[G*512+J] + biases
__global__ __launch_bounds__(256) void k_xp(
    const int* __restrict__ cap, const float* __restrict__ emb,
    const float* __restrict__ Wih, const float* __restrict__ bih, const float* __restrict__ bhh,
    float* __restrict__ xp) {
  int t = blockIdx.x;
  int g0 = blockIdx.y * 64;
  int b = threadIdx.x & 63;
  int gg = threadIdx.x >> 6;
  __shared__ float wl[64 * 32];

  int tok = cap[b * 64 + t];          // captions (64,64) row-major
  const float* er = emb + (size_t)tok * NE;

  float acc[16];
#pragma unroll
  for (int i = 0; i < 16; ++i) acc[i] = 0.f;

  for (int k0 = 0; k0 < NE; k0 += 32) {
    __syncthreads();
#pragma unroll
    for (int i = 0; i < 2; ++i) {
      int s = threadIdx.x + 256 * i;
      int gr = s >> 3, c4 = s & 7;
      *(f32x4*)(wl + gr * 32 + c4 * 4) =
          *(const f32x4*)(Wih + (size_t)(g0 + gr) * NE + k0 + c4 * 4);
    }
    __syncthreads();
    f32x4 e4[8];
#pragma unroll
    for (int u = 0; u < 8; ++u) e4[u] = *(const f32x4*)(er + k0 + u * 4);
#pragma unroll
    for (int k4 = 0; k4 < 8; ++k4) {
#pragma unroll
      for (int i = 0; i < 16; ++i) {
        f32x4 w = *(const f32x4*)(wl + (gg * 16 + i) * 32 + k4 * 4);
#pragma unroll
        for (int u = 0; u < 4; ++u) acc[i] += e4[k4][u] * w[u];
      }
    }
  }
  size_t rb = ((size_t)(t * NB) + b) * NG;
#pragma unroll
  for (int i = 0; i < 16; ++i) {
    int g = g0 + gg * 16 + i;                      // original gate row
    int np = 4 * (g & 511) + (g >> 9);             // interleaved index
    xp[rb + np] = acc[i] + bih[g] + bhh[g];
  }
}

// ---- kernel 3: ALL 63 LSTM steps, sync-free (4 blocks x 16 batch rows) ------
// h split bf16 hi+lo in LDS (fp32-exact); c in regs; gates = xp + MFMA(h, wp).
__global__ __launch_bounds__(512) void k_steps_batch(
    const float* __restrict__ xp, const unsigned short* __restrict__ wp,
    const float* __restrict__ h0, const float* __restrict__ c0,
    unsigned short* __restrict__ hsb) {
  int bb0 = blockIdx.x * 16;
  int tid = threadIdx.x;
  int lane = tid & 63;
  int w = tid >> 6;            // wave 0..7 : owns n in [w*256, w*256+256)
  int l15 = lane & 15;
  int kq = lane >> 4;          // 0..3
  int ju = tid & 127;          // unit-local within chunk
  int bq = tid >> 7;           // 0..3

  __shared__ unsigned short hhi[16 * 512];  // [bb][j] swizzled: j ^ ((bb&7)<<3)
  __shared__ unsigned short hlo[16 * 512];
  __shared__ float gbuf[16 * 512];          // gates chunk [bb][4*ju+G]

  float creg[4][4];                         // [chunk][q], unit j=ch*128+ju, bb=bq+4q
#pragma unroll
  for (int ch = 0; ch < 4; ++ch) {
    int j = ch * 128 + ju;
#pragma unroll
    for (int q = 0; q < 4; ++q) {
      int bb = bq + 4 * q;
      float h = h0[(size_t)(bb0 + bb) * NH + j];
      unsigned short hi = f2b(h);
      int hidx = bb * 512 + (j ^ ((bb & 7) << 3));
      hhi[hidx] = hi;
      hlo[hidx] = f2b(h - b2f(hi));
      creg[ch][q] = c0[(size_t)(bb0 + bb) * NH + j];
    }
  }

  for (int t = 0; t < NT; ++t) {
    __syncthreads();                        // h state ready
    // ---- MFMA phase: acc[nt] for n = w*256 + nt*16 + l15, batch=(kq*4+r) ----
    f32x4 acc[16];
#pragma unroll
    for (int nt = 0; nt < 16; ++nt) acc[nt] = (f32x4){0.f, 0.f, 0.f, 0.f};
    const unsigned short* wpw = wp + (size_t)(w * 256) * NH;
    for (int ks = 0; ks < 16; ++ks) {
      int k = ks * 32 + kq * 8;
      int aidx = l15 * 512 + (k ^ ((l15 & 7) << 3));
      short8 ahi = *(const short8*)(hhi + aidx);
      short8 alo = *(const short8*)(hlo + aidx);
#pragma unroll
      for (int nt = 0; nt < 16; ++nt) {
        short8 bf = *(const short8*)(wpw + (size_t)(nt * 16 + l15) * NH + k);
        acc[nt] = mfma16(ahi, bf, acc[nt]);
        acc[nt] = mfma16(alo, bf, acc[nt]);
      }
    }
    // ---- chunked gate redistribution + state update ----
    const float* xpt = xp + (size_t)t * NB * NG;
    unsigned short* hst = hsb + (size_t)t * NB * NH;
#pragma unroll
    for (int ch = 0; ch < 4; ++ch) {
      __syncthreads();
      if ((w >> 1) == ch) {                 // wave pair for this n-chunk
        int wl = w & 1;
#pragma unroll
        for (int nt = 0; nt < 16; ++nt) {
          int nloc = wl * 256 + nt * 16 + l15;
#pragma unroll
          for (int r = 0; r < 4; ++r)
            gbuf[(kq * 4 + r) * 512 + nloc] = acc[nt][r];
        }
      }
      __syncthreads();
      int j = ch * 128 + ju;
#pragma unroll
      for (int q = 0; q < 4; ++q) {
        int bb = bq + 4 * q;
        f32x4 g4 = *(const f32x4*)(gbuf + bb * 512 + ju * 4);
        f32x4 x4 = *(const f32x4*)(xpt + (size_t)(bb0 + bb) * NG + 4 * j);
        float gi = g4[0] + x4[0];
        float gf = g4[1] + x4[1];
        float gG = g4[2] + x4[2];
        float go = g4[3] + x4[3];
        float cn = sigm(gf) * creg[ch][q] + sigm(gi) * tanhf(gG);
        creg[ch][q] = cn;
        float h = sigm(go) * tanhf(cn);
        unsigned short hi = f2b(h);
        int hidx = bb * 512 + (j ^ ((bb & 7) << 3));
        hhi[hidx] = hi;
        hlo[hidx] = f2b(h - b2f(hi));
        hst[(size_t)(bb0 + bb) * NH + j] = hi;
      }
    }
  }
}

// ---- kernel 4: logits = hs_bf16 @ WoutBf^T + bout, f32 out, (b,t,v) ---------
__global__ __launch_bounds__(256) void k_logits_m(
    const unsigned short* __restrict__ hsb, const unsigned short* __restrict__ wb,
    const float* __restrict__ bout, float* __restrict__ out) {
  __shared__ unsigned short As[128 * 64];
  __shared__ unsigned short Bs[128 * 64];
  __shared__ float cst[4][16][68];
  int m0 = blockIdx.x * 128;
  int n0 = blockIdx.y * 128;
  int tid = threadIdx.x;
  int lane = tid & 63;
  int l15 = lane & 15;
  int kl = (lane >> 4) * 8;
  int w = tid >> 6;
  int wr = w >> 1, wc = w & 1;

  f32x4 acc[4][4];
#pragma unroll
  for (int i = 0; i < 4; ++i)
#pragma unroll
    for (int j = 0; j < 4; ++j) acc[i][j] = (f32x4){0.f, 0.f, 0.f, 0.f};

  for (int k0 = 0; k0 < NH; k0 += 64) {
    short8 ta[4], tb[4];
#pragma unroll
    for (int cc = 0; cc < 4; ++cc) {
      int idx = cc * 2048 + tid * 8;
      int row = idx >> 6;
      int ke = idx & 63;
      ta[cc] = *(const short8*)(hsb + (size_t)(m0 + row) * NH + k0 + ke);
      tb[cc] = *(const short8*)(wb + (size_t)(n0 + row) * NH + k0 + ke);
    }
    __syncthreads();
#pragma unroll
    for (int cc = 0; cc < 4; ++cc) {
      int idx = cc * 2048 + tid * 8;
      int row = idx >> 6;
      int ke = (idx & 63) ^ ((row & 7) << 3);
      *(short8*)(As + row * 64 + ke) = ta[cc];
      *(short8*)(Bs + row * 64 + ke) = tb[cc];
    }
    __syncthreads();
#pragma unroll
    for (int kk = 0; kk < 64; kk += 32) {
      short8 a[4], b[4];
#pragma unroll
      for (int mi = 0; mi < 4; ++mi) {
        int row = wr * 64 + mi * 16 + l15;
        a[mi] = *(const short8*)(As + row * 64 + ((kk + kl) ^ ((row & 7) << 3)));
      }
#pragma unroll
      for (int ni = 0; ni < 4; ++ni) {
        int row = wc * 64 + ni * 16 + l15;
        b[ni] = *(const short8*)(Bs + row * 64 + ((kk + kl) ^ ((row & 7) << 3)));
      }
#pragma unroll
      for (int mi = 0; mi < 4; ++mi)
#pragma unroll
        for (int ni = 0; ni < 4; ++ni)
          acc[mi][ni] = mfma16(a[mi], b[ni], acc[mi][ni]);
    }
  }

  // epilogue: per-wave LDS transpose -> f32x4 coalesced stores
  f32x4 bo4 = *(const f32x4*)(bout + n0 + wc * 64 + l15 * 4);
#pragma unroll
  for (int mi = 0; mi < 4; ++mi) {
    __syncthreads();
#pragma unroll
    for (int ni = 0; ni < 4; ++ni)
#pragma unroll
      for (int r = 0; r < 4; ++r)
        cst[w][(lane >> 4) * 4 + r][ni * 16 + l15] = acc[mi][ni][r];
    __syncthreads();
#pragma unroll
    for (int p = 0; p < 4; ++p) {
      int row16 = p * 4 + (lane >> 4);
      int m = m0 + wr * 64 + mi * 16 + row16;
      f32x4 v = *(const f32x4*)&cst[w][row16][l15 * 4];
#pragma unroll
      for (int u = 0; u < 4; ++u) v[u] += bo4[u];
      if (m < NT * NB) {
        int t = m >> 6, b = m & 63;
        *(f32x4*)(out + (size_t)b * (NT * NV) + (size_t)t * NV + n0 + wc * 64 + l15 * 4) = v;
      }
    }
  }
}

extern "C" void kernel_launch(void* const* d_in, const int* in_sizes, int n_in,
                              void* d_out, int out_size, void* d_ws, size_t ws_size,
                              hipStream_t stream) {
  const float* enc  = (const float*)d_in[0];
  const int*   cap  = (const int*)d_in[1];
  const float* emb  = (const float*)d_in[2];
  const float* Wih  = (const float*)d_in[3];
  const float* Whh  = (const float*)d_in[4];
  const float* bih  = (const float*)d_in[5];
  const float* bhh  = (const float*)d_in[6];
  const float* Wh   = (const float*)d_in[7];
  const float* bh   = (const float*)d_in[8];
  const float* Wc   = (const float*)d_in[9];
  const float* bc   = (const float*)d_in[10];
  const float* Wout = (const float*)d_in[11];
  const float* bout = (const float*)d_in[12];
  float* out = (float*)d_out;

  char* ws = (char*)d_ws;
  constexpr size_t C_OFF   = 0;
  constexpr size_t HA_OFF  = C_OFF + (size_t)NB * NH * 4;          // 131072
  constexpr size_t HSB_OFF = HA_OFF + (size_t)NB * NH * 4;         // 262144
  constexpr size_t WB_OFF  = HSB_OFF + (size_t)4096 * NH * 2;      // +4 MiB
  constexpr size_t WP_OFF  = WB_OFF + (size_t)NV * NH * 2;         // +32.8 MB
  constexpr size_t XP_OFF  = WP_OFF + (size_t)NG * NH * 2;         // +2 MiB
  float* c  = (float*)(ws + C_OFF);
  float* hA = (float*)(ws + HA_OFF);
  unsigned short* hsb = (unsigned short*)(ws + HSB_OFF);
  unsigned short* wb  = (unsigned short*)(ws + WB_OFF);
  unsigned short* wp  = (unsigned short*)(ws + WP_OFF);
  float* xp = (float*)(ws + XP_OFF);

  k_prep<<<1024, 256, 0, stream>>>(Wout, wb, hsb);
  k_prep2<<<256, 256, 0, stream>>>(Whh, wp);
  k_init<<<NB, 256, 0, stream>>>(enc, Wh, bh, Wc, bc, c, hA);

  dim3 g2(NT, NG / 64);
  k_xp<<<g2, 256, 0, stream>>>(cap, emb, Wih, bih, bhh, xp);

  k_steps_batch<<<4, 512, 0, stream>>>(xp, wp, hA, c, hsb);

  dim3 g4(32, NV / 128);
  k_logits_m<<<g4, 256, 0, stream>>>(hsb, wb, bout, out);
}

// Round 20
// 1345.450 us; speedup vs baseline: 3.5904x; 3.5904x over previous
//
#include <hip/hip_runtime.h>
#include <hip/hip_bf16.h>
#include <stdint.h>
#include <math.h>

typedef __attribute__((ext_vector_type(4))) float f32x4;
typedef __attribute__((ext_vector_type(8))) short short8;   // 8 bf16

#define NB 64      // batch
#define NT 63      // time steps (captions[:, :-1])
#define NE 512     // embed dim
#define NH 512     // hidden dim
#define NV 32000   // vocab
#define NG 2048    // 4*H gates
#define NBLK 16    // persistent step-kernel blocks

__device__ __forceinline__ float sigm(float x) { return 1.f / (1.f + expf(-x)); }
__device__ __forceinline__ unsigned short f2b(float f) {   // f32 -> bf16 RNE
  union { float f; uint32_t u; } x; x.f = f;
  uint32_t r = x.u + 0x7FFF + ((x.u >> 16) & 1);
  return (unsigned short)(r >> 16);
}
__device__ __forceinline__ float b2f(unsigned short s) {
  union { uint32_t u; float f; } x; x.u = ((uint32_t)s) << 16; return x.f;
}
__device__ __forceinline__ f32x4 mfma16(short8 a, short8 b, f32x4 c) {
  return __builtin_amdgcn_mfma_f32_16x16x32_bf16(a, b, c, 0, 0, 0);
}

// ---- kernel 0a: Wout f32 -> bf16; zero hsb pad rows (incl. sync counter) ----
__global__ __launch_bounds__(256) void k_prep(
    const float* __restrict__ Wout, unsigned short* __restrict__ wb,
    unsigned short* __restrict__ hsb) {
  const int n4 = NV * NH / 4;
  for (int i = blockIdx.x * 256 + threadIdx.x; i < n4; i += gridDim.x * 256) {
    f32x4 v = *(const f32x4*)(Wout + (size_t)i * 4);
    unsigned short o[4];
#pragma unroll
    for (int u = 0; u < 4; ++u) o[u] = f2b(v[u]);
    *(uint64_t*)(wb + (size_t)i * 4) = *(const uint64_t*)o;
  }
  for (int i = blockIdx.x * 256 + threadIdx.x; i < 64 * NH; i += gridDim.x * 256)
    hsb[(size_t)(NT * NB) * NH + i] = 0;   // pad rows 4032..4095 (sync ctr lives here)
}

// ---- kernel 0b: pack W_hh -> bf16, gate-interleaved rows n' = 4*J + G -------
__global__ __launch_bounds__(256) void k_prep2(
    const float* __restrict__ Whh, unsigned short* __restrict__ wp) {
  const int n4 = NG * NH / 4;
  for (int i4 = blockIdx.x * 256 + threadIdx.x; i4 < n4; i4 += gridDim.x * 256) {
    int r = i4 >> 7;                 // original row: G*512 + J
    int k4 = (i4 & 127) * 4;
    int np = 4 * (r & 511) + (r >> 9);
    f32x4 v = *(const f32x4*)(Whh + (size_t)r * NH + k4);
    unsigned short o[4];
#pragma unroll
    for (int u = 0; u < 4; ++u) o[u] = f2b(v[u]);
    *(uint64_t*)(wp + (size_t)np * NH + k4) = *(const uint64_t*)o;
  }
}

// ---- kernel 1: h0 -> hA (bf16 hi/lo); c0 -> f32 overlay on hB region --------
__global__ __launch_bounds__(256) void k_init(
    const float* __restrict__ enc, const float* __restrict__ Wh, const float* __restrict__ bh,
    const float* __restrict__ Wc, const float* __restrict__ bc,
    float* __restrict__ c0f, unsigned short* __restrict__ hAhi, unsigned short* __restrict__ hAlo) {
  int b = blockIdx.x;
  __shared__ float se[NE];
  for (int e = threadIdx.x; e < NE; e += 256) se[e] = enc[b * NE + e];
  __syncthreads();
  for (int j = threadIdx.x; j < NH; j += 256) {
    float dh = 0.f, dc = 0.f;
    const float* wh = Wh + (size_t)j * NE;
    const float* wc = Wc + (size_t)j * NE;
    for (int e = 0; e < NE; e += 4) {
      f32x4 vh = *(const f32x4*)(wh + e);
      f32x4 vc = *(const f32x4*)(wc + e);
#pragma unroll
      for (int u = 0; u < 4; ++u) {
        float x = se[e + u];
        dh += x * vh[u];
        dc += x * vc[u];
      }
    }
    float h = tanhf(dh + bh[j]);
    unsigned short hi = f2b(h);
    hAhi[b * NH + j] = hi;
    hAlo[b * NH + j] = f2b(h - b2f(hi));
    c0f[b * NH + j] = tanhf(dc + bc[j]);
  }
}

// ---- kernel 2 (f32): xp[t][b][4*J+G] = emb(cap[b][t]) . W_ih[G*512+J] + biases
__global__ __launch_bounds__(256) void k_xp(
    const int* __restrict__ cap, const float* __restrict__ emb,
    const float* __restrict__ Wih, const float* __restrict__ bih, const float* __restrict__ bhh,
    float* __restrict__ xp) {
  int t = blockIdx.x;
  int g0 = blockIdx.y * 64;
  int b = threadIdx.x & 63;
  int gg = threadIdx.x >> 6;
  __shared__ float wl[64 * 32];

  int tok = cap[b * 64 + t];          // captions (64,64) row-major
  const float* er = emb + (size_t)tok * NE;

  float acc[16];
#pragma unroll
  for (int i = 0; i < 16; ++i) acc[i] = 0.f;

  for (int k0 = 0; k0 < NE; k0 += 32) {
    __syncthreads();
#pragma unroll
    for (int i = 0; i < 2; ++i) {
      int s = threadIdx.x + 256 * i;
      int gr = s >> 3, c4 = s & 7;
      *(f32x4*)(wl + gr * 32 + c4 * 4) =
          *(const f32x4*)(Wih + (size_t)(g0 + gr) * NE + k0 + c4 * 4);
    }
    __syncthreads();
    f32x4 e4[8];
#pragma unroll
    for (int u = 0; u < 8; ++u) e4[u] = *(const f32x4*)(er + k0 + u * 4);
#pragma unroll
    for (int k4 = 0; k4 < 8; ++k4) {
#pragma unroll
      for (int i = 0; i < 16; ++i) {
        f32x4 w = *(const f32x4*)(wl + (gg * 16 + i) * 32 + k4 * 4);
#pragma unroll
        for (int u = 0; u < 4; ++u) acc[i] += e4[k4][u] * w[u];
      }
    }
  }
  size_t rb = ((size_t)(t * NB) + b) * NG;
#pragma unroll
  for (int i = 0; i < 16; ++i) {
    int g = g0 + gg * 16 + i;                      // original gate row
    int np = 4 * (g & 511) + (g >> 9);             // interleaved index
    xp[rb + np] = acc[i] + bih[g] + bhh[g];
  }
}

// ---- kernel 3: persistent gate-split LSTM, 16 blocks, epoch-sync ------------
// Block B owns units J in [B*32, B*32+32) (wp rows [B*128, B*128+128)).
// Per step: stage full h (hi/lo) to LDS, MFMA gates, update state, sync.
__global__ __launch_bounds__(512, 1) void k_steps_p(
    const float* __restrict__ xp, const unsigned short* __restrict__ wp,
    unsigned short* __restrict__ hAhi, unsigned short* __restrict__ hAlo,
    unsigned short* __restrict__ hBhi, unsigned short* __restrict__ hBlo,
    const float* __restrict__ c0f, unsigned short* __restrict__ hsb,
    int* __restrict__ syncc) {
  int tid = threadIdx.x;
  int lane = tid & 63;
  int w = tid >> 6;            // wave 0..7
  int l15 = lane & 15;
  int kq = lane >> 4;          // 0..3
  int mloc = l15, ju = kq;
  int B = blockIdx.x;
  int J = B * 32 + w * 4 + ju; // this thread's hidden unit (update phase)

  __shared__ unsigned short hh[64 * 512];  // staged h hi, swizzled (64KB)
  __shared__ unsigned short hl[64 * 512];  // staged h lo (64KB)
  __shared__ float gb[8][272];             // per-wave gate transpose (16x17)

  float creg[4];
#pragma unroll
  for (int mi = 0; mi < 4; ++mi)
    creg[mi] = c0f[(size_t)(mi * 16 + mloc) * NH + J];

  for (int t = 0; t < NT; ++t) {
    const unsigned short* rhi = (t & 1) ? hBhi : hAhi;
    const unsigned short* rlo = (t & 1) ? hBlo : hAlo;
    unsigned short* whi2 = (t & 1) ? hAhi : hBhi;
    unsigned short* wlo2 = (t & 1) ? hAlo : hBlo;

    // ---- stage h into LDS (each wave: one row per q-iter, coalesced) ----
#pragma unroll
    for (int q = 0; q < 8; ++q) {
      int m = q * 8 + w;
      int ke = lane * 8;
      int d = m * 512 + (ke ^ (8 * (m & 7)));
      *(short8*)(hh + d) = *(const short8*)(rhi + (size_t)m * 512 + ke);
      *(short8*)(hl + d) = *(const short8*)(rlo + (size_t)m * 512 + ke);
    }
    __syncthreads();

    // ---- MFMA: gates[m][n] for n = wave's 16 wp rows, m = 64 batch ----
    f32x4 acc[4];
#pragma unroll
    for (int mi = 0; mi < 4; ++mi) acc[mi] = (f32x4){0.f, 0.f, 0.f, 0.f};
    const unsigned short* wpw = wp + ((size_t)B * 128 + w * 16 + l15) * 512;
    for (int ks = 0; ks < 16; ++ks) {
      int k = ks * 32 + kq * 8;
      short8 bf = *(const short8*)(wpw + k);
#pragma unroll
      for (int mi = 0; mi < 4; ++mi) {
        int m = mi * 16 + l15;
        int aoff = m * 512 + (k ^ (8 * (m & 7)));
        acc[mi] = mfma16(*(const short8*)(hh + aoff), bf, acc[mi]);
        acc[mi] = mfma16(*(const short8*)(hl + aoff), bf, acc[mi]);
      }
    }

    // ---- per-wave transpose + state update (c in regs) ----
    const float* xpt = xp + (size_t)t * NB * NG;
    unsigned short* hst = hsb + (size_t)t * NB * NH;
#pragma unroll
    for (int mi = 0; mi < 4; ++mi) {
#pragma unroll
      for (int r = 0; r < 4; ++r)
        gb[w][(kq * 4 + r) * 17 + l15] = acc[mi][r];
      // same-wave LDS RAW: in-order DS + compiler lgkmcnt
      int m = mi * 16 + mloc;
      float g0 = gb[w][mloc * 17 + ju * 4 + 0];
      float g1 = gb[w][mloc * 17 + ju * 4 + 1];
      float g2 = gb[w][mloc * 17 + ju * 4 + 2];
      float g3 = gb[w][mloc * 17 + ju * 4 + 3];
      f32x4 x4 = *(const f32x4*)(xpt + (size_t)m * NG + 4 * J);
      float gi = g0 + x4[0];
      float gf = g1 + x4[1];
      float gG = g2 + x4[2];
      float go = g3 + x4[3];
      float cn = sigm(gf) * creg[mi] + sigm(gi) * tanhf(gG);
      creg[mi] = cn;
      float h = sigm(go) * tanhf(cn);
      unsigned short hi = f2b(h);
      whi2[(size_t)m * NH + J] = hi;
      wlo2[(size_t)m * NH + J] = f2b(h - b2f(hi));
      hst[(size_t)m * NH + J] = hi;
    }

    // ---- epoch sync across 16 blocks (skip after last step) ----
    if (t < NT - 1) {
      __syncthreads();                       // drains this block's stores
      if (tid == 0) {
        __threadfence();                     // release: writes device-visible
        __hip_atomic_fetch_add(syncc, 1, __ATOMIC_RELEASE, __HIP_MEMORY_SCOPE_AGENT);
        while (__hip_atomic_load(syncc, __ATOMIC_ACQUIRE, __HIP_MEMORY_SCOPE_AGENT)
               < NBLK * (t + 1)) {}
        __threadfence();                     // acquire: invalidate stale cache
      }
      __syncthreads();
    }
  }
}

// ---- kernel 4: logits = hs_bf16 @ WoutBf^T + bout, f32 out, (b,t,v) ---------
__global__ __launch_bounds__(256) void k_logits_m(
    const unsigned short* __restrict__ hsb, const unsigned short* __restrict__ wb,
    const float* __restrict__ bout, float* __restrict__ out) {
  __shared__ unsigned short As[128 * 64];
  __shared__ unsigned short Bs[128 * 64];
  __shared__ float cst[4][16][68];
  int m0 = blockIdx.x * 128;
  int n0 = blockIdx.y * 128;
  int tid = threadIdx.x;
  int lane = tid & 63;
  int l15 = lane & 15;
  int kl = (lane >> 4) * 8;
  int w = tid >> 6;
  int wr = w >> 1, wc = w & 1;

  f32x4 acc[4][4];
#pragma unroll
  for (int i = 0; i < 4; ++i)
#pragma unroll
    for (int j = 0; j < 4; ++j) acc[i][j] = (f32x4){0.f, 0.f, 0.f, 0.f};

  for (int k0 = 0; k0 < NH; k0 += 64) {
    short8 ta[4], tb[4];
#pragma unroll
    for (int cc = 0; cc < 4; ++cc) {
      int idx = cc * 2048 + tid * 8;
      int row = idx >> 6;
      int ke = idx & 63;
      ta[cc] = *(const short8*)(hsb + (size_t)(m0 + row) * NH + k0 + ke);
      tb[cc] = *(const short8*)(wb + (size_t)(n0 + row) * NH + k0 + ke);
    }
    __syncthreads();
#pragma unroll
    for (int cc = 0; cc < 4; ++cc) {
      int idx = cc * 2048 + tid * 8;
      int row = idx >> 6;
      int ke = (idx & 63) ^ ((row & 7) << 3);
      *(short8*)(As + row * 64 + ke) = ta[cc];
      *(short8*)(Bs + row * 64 + ke) = tb[cc];
    }
    __syncthreads();
#pragma unroll
    for (int kk = 0; kk < 64; kk += 32) {
      short8 a[4], b[4];
#pragma unroll
      for (int mi = 0; mi < 4; ++mi) {
        int row = wr * 64 + mi * 16 + l15;
        a[mi] = *(const short8*)(As + row * 64 + ((kk + kl) ^ ((row & 7) << 3)));
      }
#pragma unroll
      for (int ni = 0; ni < 4; ++ni) {
        int row = wc * 64 + ni * 16 + l15;
        b[ni] = *(const short8*)(Bs + row * 64 + ((kk + kl) ^ ((row & 7) << 3)));
      }
#pragma unroll
      for (int mi = 0; mi < 4; ++mi)
#pragma unroll
        for (int ni = 0; ni < 4; ++ni)
          acc[mi][ni] = mfma16(a[mi], b[ni], acc[mi][ni]);
    }
  }

  // epilogue: per-wave LDS transpose -> f32x4 coalesced stores
  f32x4 bo4 = *(const f32x4*)(bout + n0 + wc * 64 + l15 * 4);
#pragma unroll
  for (int mi = 0; mi < 4; ++mi) {
    __syncthreads();
#pragma unroll
    for (int ni = 0; ni < 4; ++ni)
#pragma unroll
      for (int r = 0; r < 4; ++r)
        cst[w][(lane >> 4) * 4 + r][ni * 16 + l15] = acc[mi][ni][r];
    __syncthreads();
#pragma unroll
    for (int p = 0; p < 4; ++p) {
      int row16 = p * 4 + (lane >> 4);
      int m = m0 + wr * 64 + mi * 16 + row16;
      f32x4 v = *(const f32x4*)&cst[w][row16][l15 * 4];
#pragma unroll
      for (int u = 0; u < 4; ++u) v[u] += bo4[u];
      if (m < NT * NB) {
        int t = m >> 6, b = m & 63;
        *(f32x4*)(out + (size_t)b * (NT * NV) + (size_t)t * NV + n0 + wc * 64 + l15 * 4) = v;
      }
    }
  }
}

extern "C" void kernel_launch(void* const* d_in, const int* in_sizes, int n_in,
                              void* d_out, int out_size, void* d_ws, size_t ws_size,
                              hipStream_t stream) {
  const float* enc  = (const float*)d_in[0];
  const int*   cap  = (const int*)d_in[1];
  const float* emb  = (const float*)d_in[2];
  const float* Wih  = (const float*)d_in[3];
  const float* Whh  = (const float*)d_in[4];
  const float* bih  = (const float*)d_in[5];
  const float* bhh  = (const float*)d_in[6];
  const float* Wh   = (const float*)d_in[7];
  const float* bh   = (const float*)d_in[8];
  const float* Wc   = (const float*)d_in[9];
  const float* bc   = (const float*)d_in[10];
  const float* Wout = (const float*)d_in[11];
  const float* bout = (const float*)d_in[12];
  float* out = (float*)d_out;

  // workspace layout — total 72,351,744 B (== round-19's proven footprint)
  char* ws = (char*)d_ws;
  constexpr size_t HA_HI = 0;                                  // 65,536
  constexpr size_t HA_LO = HA_HI + 65536;
  constexpr size_t HB_HI = HA_LO + 65536;                      // c0 f32 overlay
  constexpr size_t HB_LO = HB_HI + 65536;
  constexpr size_t HSB_OFF = HB_LO + 65536;                    // 262,144
  constexpr size_t WB_OFF  = HSB_OFF + (size_t)4096 * NH * 2;  // 4,456,448
  constexpr size_t WP_OFF  = WB_OFF + (size_t)NV * NH * 2;     // 37,224,448
  constexpr size_t XP_OFF  = WP_OFF + (size_t)NG * NH * 2;     // 39,321,600
  unsigned short* hAhi = (unsigned short*)(ws + HA_HI);
  unsigned short* hAlo = (unsigned short*)(ws + HA_LO);
  unsigned short* hBhi = (unsigned short*)(ws + HB_HI);
  unsigned short* hBlo = (unsigned short*)(ws + HB_LO);
  float* c0f = (float*)(ws + HB_HI);                           // 128KB overlay
  unsigned short* hsb = (unsigned short*)(ws + HSB_OFF);
  unsigned short* wb  = (unsigned short*)(ws + WB_OFF);
  unsigned short* wp  = (unsigned short*)(ws + WP_OFF);
  float* xp = (float*)(ws + XP_OFF);
  int* syncc = (int*)(ws + HSB_OFF + (size_t)(NT * NB) * NH * 2);  // hsb pad row

  k_prep<<<1024, 256, 0, stream>>>(Wout, wb, hsb);   // also zeroes syncc
  k_prep2<<<256, 256, 0, stream>>>(Whh, wp);
  k_init<<<NB, 256, 0, stream>>>(enc, Wh, bh, Wc, bc, c0f, hAhi, hAlo);

  dim3 g2(NT, NG / 64);
  k_xp<<<g2, 256, 0, stream>>>(cap, emb, Wih, bih, bhh, xp);

  k_steps_p<<<NBLK, 512, 0, stream>>>(xp, wp, hAhi, hAlo, hBhi, hBlo, c0f, hsb, syncc);

  dim3 g4(32, NV / 128);
  k_logits_m<<<g4, 256, 0, stream>>>(hsb, wb, bout, out);
}

// Round 21
// 1128.803 us; speedup vs baseline: 4.2795x; 1.1919x over previous
//
#include <hip/hip_runtime.h>
#include <hip/hip_bf16.h>
#include <stdint.h>
#include <math.h>

typedef __attribute__((ext_vector_type(4))) float f32x4;
typedef __attribute__((ext_vector_type(8))) short short8;   // 8 bf16

#define NB 64      // batch
#define NT 63      // time steps (captions[:, :-1])
#define NE 512     // embed dim
#define NH 512     // hidden dim
#define NV 32000   // vocab
#define NG 2048    // 4*H gates
#define GQ 4       // batch groups (16 rows each)
#define GS 16      // gate splits  (32 units each)

__device__ __forceinline__ float sigm(float x) { return 1.f / (1.f + expf(-x)); }
__device__ __forceinline__ unsigned short f2b(float f) {   // f32 -> bf16 RNE
  union { float f; uint32_t u; } x; x.f = f;
  uint32_t r = x.u + 0x7FFF + ((x.u >> 16) & 1);
  return (unsigned short)(r >> 16);
}
__device__ __forceinline__ float b2f(unsigned short s) {
  union { uint32_t u; float f; } x; x.u = ((uint32_t)s) << 16; return x.f;
}
__device__ __forceinline__ f32x4 mfma16(short8 a, short8 b, f32x4 c) {
  return __builtin_amdgcn_mfma_f32_16x16x32_bf16(a, b, c, 0, 0, 0);
}

// ---- kernel 0a: Wout f32 -> bf16; zero hsb pad rows (incl. sync counters) ---
__global__ __launch_bounds__(256) void k_prep(
    const float* __restrict__ Wout, unsigned short* __restrict__ wb,
    unsigned short* __restrict__ hsb) {
  const int n4 = NV * NH / 4;
  for (int i = blockIdx.x * 256 + threadIdx.x; i < n4; i += gridDim.x * 256) {
    f32x4 v = *(const f32x4*)(Wout + (size_t)i * 4);
    unsigned short o[4];
#pragma unroll
    for (int u = 0; u < 4; ++u) o[u] = f2b(v[u]);
    *(uint64_t*)(wb + (size_t)i * 4) = *(const uint64_t*)o;
  }
  for (int i = blockIdx.x * 256 + threadIdx.x; i < 64 * NH; i += gridDim.x * 256)
    hsb[(size_t)(NT * NB) * NH + i] = 0;   // pad rows (sync counters live here)
}

// ---- kernel 0b: pack W_hh -> bf16, gate-interleaved rows n' = 4*J + G -------
__global__ __launch_bounds__(256) void k_prep2(
    const float* __restrict__ Whh, unsigned short* __restrict__ wp) {
  const int n4 = NG * NH / 4;
  for (int i4 = blockIdx.x * 256 + threadIdx.x; i4 < n4; i4 += gridDim.x * 256) {
    int r = i4 >> 7;                 // original row: G*512 + J
    int k4 = (i4 & 127) * 4;
    int np = 4 * (r & 511) + (r >> 9);
    f32x4 v = *(const f32x4*)(Whh + (size_t)r * NH + k4);
    unsigned short o[4];
#pragma unroll
    for (int u = 0; u < 4; ++u) o[u] = f2b(v[u]);
    *(uint64_t*)(wp + (size_t)np * NH + k4) = *(const uint64_t*)o;
  }
}

// ---- kernel 1: h0 -> hA (bf16 hi/lo); c0 -> f32 overlay on hB region --------
__global__ __launch_bounds__(256) void k_init(
    const float* __restrict__ enc, const float* __restrict__ Wh, const float* __restrict__ bh,
    const float* __restrict__ Wc, const float* __restrict__ bc,
    float* __restrict__ c0f, unsigned short* __restrict__ hAhi, unsigned short* __restrict__ hAlo) {
  int b = blockIdx.x;
  __shared__ float se[NE];
  for (int e = threadIdx.x; e < NE; e += 256) se[e] = enc[b * NE + e];
  __syncthreads();
  for (int j = threadIdx.x; j < NH; j += 256) {
    float dh = 0.f, dc = 0.f;
    const float* wh = Wh + (size_t)j * NE;
    const float* wc = Wc + (size_t)j * NE;
    for (int e = 0; e < NE; e += 4) {
      f32x4 vh = *(const f32x4*)(wh + e);
      f32x4 vc = *(const f32x4*)(wc + e);
#pragma unroll
      for (int u = 0; u < 4; ++u) {
        float x = se[e + u];
        dh += x * vh[u];
        dc += x * vc[u];
      }
    }
    float h = tanhf(dh + bh[j]);
    unsigned short hi = f2b(h);
    hAhi[b * NH + j] = hi;
    hAlo[b * NH + j] = f2b(h - b2f(hi));
    c0f[b * NH + j] = tanhf(dc + bc[j]);
  }
}

// ---- kernel 2 (f32): xp[t][b][4*J+G] = emb(cap[b][t]) . W_ih[G*512+J] + biases
__global__ __launch_bounds__(256) void k_xp(
    const int* __restrict__ cap, const float* __restrict__ emb,
    const float* __restrict__ Wih, const float* __restrict__ bih, const float* __restrict__ bhh,
    float* __restrict__ xp) {
  int t = blockIdx.x;
  int g0 = blockIdx.y * 64;
  int b = threadIdx.x & 63;
  int gg = threadIdx.x >> 6;
  __shared__ float wl[64 * 32];

  int tok = cap[b * 64 + t];          // captions (64,64) row-major
  const float* er = emb + (size_t)tok * NE;

  float acc[16];
#pragma unroll
  for (int i = 0; i < 16; ++i) acc[i] = 0.f;

  for (int k0 = 0; k0 < NE; k0 += 32) {
    __syncthreads();
#pragma unroll
    for (int i = 0; i < 2; ++i) {
      int s = threadIdx.x + 256 * i;
      int gr = s >> 3, c4 = s & 7;
      *(f32x4*)(wl + gr * 32 + c4 * 4) =
          *(const f32x4*)(Wih + (size_t)(g0 + gr) * NE + k0 + c4 * 4);
    }
    __syncthreads();
    f32x4 e4[8];
#pragma unroll
    for (int u = 0; u < 8; ++u) e4[u] = *(const f32x4*)(er + k0 + u * 4);
#pragma unroll
    for (int k4 = 0; k4 < 8; ++k4) {
#pragma unroll
      for (int i = 0; i < 16; ++i) {
        f32x4 w = *(const f32x4*)(wl + (gg * 16 + i) * 32 + k4 * 4);
#pragma unroll
        for (int u = 0; u < 4; ++u) acc[i] += e4[k4][u] * w[u];
      }
    }
  }
  size_t rb = ((size_t)(t * NB) + b) * NG;
#pragma unroll
  for (int i = 0; i < 16; ++i) {
    int g = g0 + gg * 16 + i;                      // original gate row
    int np = 4 * (g & 511) + (g >> 9);             // interleaved index
    xp[rb + np] = acc[i] + bih[g] + bhh[g];
  }
}

// ---- kernel 3: persistent LSTM, 64 blocks = 4 batch-groups x 16 gate-splits -
// Block (q,s): batch rows [q*16,q*16+16), units [s*32,s*32+32).
// Sync only within the 16-block gate-split group (batch groups independent).
__global__ __launch_bounds__(512, 1) void k_steps_p(
    const float* __restrict__ xp, const unsigned short* __restrict__ wp,
    unsigned short* __restrict__ hAhi, unsigned short* __restrict__ hAlo,
    unsigned short* __restrict__ hBhi, unsigned short* __restrict__ hBlo,
    const float* __restrict__ c0f, unsigned short* __restrict__ hsb,
    int* __restrict__ syncc) {
  int tid = threadIdx.x;
  int lane = tid & 63;
  int w = tid >> 6;            // wave 0..7
  int l15 = lane & 15;
  int kq = lane >> 4;          // 0..3
  int q = blockIdx.x >> 4;     // batch group
  int s = blockIdx.x & 15;     // gate split
  int m0 = q * 16;
  int ju = tid & 31;           // unit local (update phase)
  int mu = tid >> 5;           // batch local (update phase)
  int J = s * 32 + ju;

  __shared__ unsigned short hh[16 * 512];  // 16KB staged h hi (swizzled)
  __shared__ unsigned short hl[16 * 512];  // 16KB staged h lo
  __shared__ float gb[128][17];            // gate transpose

  float creg = c0f[(size_t)(m0 + mu) * NH + J];
  int* cnt = syncc + q * 32;               // 128B-spaced per-group counters
  const unsigned short* wpw = wp + ((size_t)s * 128 + w * 16 + l15) * 512;

  for (int t = 0; t < NT; ++t) {
    const unsigned short* rhi = (t & 1) ? hBhi : hAhi;
    const unsigned short* rlo = (t & 1) ? hBlo : hAlo;
    unsigned short* whi2 = (t & 1) ? hAhi : hBhi;
    unsigned short* wlo2 = (t & 1) ? hAlo : hBlo;

    // prefetch this step's xp gate quad (independent of other blocks)
    f32x4 x4 = *(const f32x4*)(xp + ((size_t)t * NB + m0 + mu) * NG + 4 * J);

    // ---- stage h rows [m0, m0+16) into LDS (coalesced 16B/lane) ----
#pragma unroll
    for (int rdd = 0; rdd < 2; ++rdd) {
      int idx = tid + rdd * 512;           // 0..1023
      int m = idx >> 6;                    // 0..15
      int ke = (idx & 63) * 8;             // element offset
      int d = m * 512 + (ke ^ (8 * (m & 7)));
      *(short8*)(hh + d) = *(const short8*)(rhi + (size_t)(m0 + m) * 512 + ke);
      *(short8*)(hl + d) = *(const short8*)(rlo + (size_t)(m0 + m) * 512 + ke);
    }
    __syncthreads();

    // ---- MFMA: gates[m 0..15][n = w*16+l15] over K=512, split hi/lo ----
    f32x4 acc = (f32x4){0.f, 0.f, 0.f, 0.f};
    for (int ks = 0; ks < 16; ++ks) {
      int k = ks * 32 + kq * 8;
      short8 bf = *(const short8*)(wpw + k);
      int aoff = l15 * 512 + (k ^ (8 * (l15 & 7)));
      acc = mfma16(*(const short8*)(hh + aoff), bf, acc);
      acc = mfma16(*(const short8*)(hl + aoff), bf, acc);
    }

    // ---- transpose to [n_loc][m] and update state ----
#pragma unroll
    for (int r = 0; r < 4; ++r)
      gb[w * 16 + l15][kq * 4 + r] = acc[r];
    __syncthreads();

    float g0 = gb[4 * ju + 0][mu];
    float g1 = gb[4 * ju + 1][mu];
    float g2 = gb[4 * ju + 2][mu];
    float g3 = gb[4 * ju + 3][mu];
    float gi = g0 + x4[0];
    float gf = g1 + x4[1];
    float gG = g2 + x4[2];
    float go = g3 + x4[3];
    float cn = sigm(gf) * creg + sigm(gi) * tanhf(gG);
    creg = cn;
    float h = sigm(go) * tanhf(cn);
    unsigned short hi = f2b(h);
    size_t hoff = (size_t)(m0 + mu) * NH + J;
    whi2[hoff] = hi;
    wlo2[hoff] = f2b(h - b2f(hi));
    hsb[(size_t)t * NB * NH + hoff] = hi;

    // ---- epoch sync within the 16-block group ----
    if (t < NT - 1) {
      __syncthreads();                     // block's stores issued
      if (tid == 0) {
        __threadfence();                   // release
        __hip_atomic_fetch_add(cnt, 1, __ATOMIC_RELEASE, __HIP_MEMORY_SCOPE_AGENT);
        while (__hip_atomic_load(cnt, __ATOMIC_ACQUIRE, __HIP_MEMORY_SCOPE_AGENT)
               < GS * (t + 1)) {}
        __threadfence();                   // acquire
      }
      __syncthreads();
    }
  }
}

// ---- kernel 4: logits = hs_bf16 @ WoutBf^T + bout, f32 out, (b,t,v) ---------
__global__ __launch_bounds__(256) void k_logits_m(
    const unsigned short* __restrict__ hsb, const unsigned short* __restrict__ wb,
    const float* __restrict__ bout, float* __restrict__ out) {
  __shared__ unsigned short As[128 * 64];
  __shared__ unsigned short Bs[128 * 64];
  __shared__ float cst[4][16][68];
  int m0 = blockIdx.x * 128;
  int n0 = blockIdx.y * 128;
  int tid = threadIdx.x;
  int lane = tid & 63;
  int l15 = lane & 15;
  int kl = (lane >> 4) * 8;
  int w = tid >> 6;
  int wr = w >> 1, wc = w & 1;

  f32x4 acc[4][4];
#pragma unroll
  for (int i = 0; i < 4; ++i)
#pragma unroll
    for (int j = 0; j < 4; ++j) acc[i][j] = (f32x4){0.f, 0.f, 0.f, 0.f};

  for (int k0 = 0; k0 < NH; k0 += 64) {
    short8 ta[4], tb[4];
#pragma unroll
    for (int cc = 0; cc < 4; ++cc) {
      int idx = cc * 2048 + tid * 8;
      int row = idx >> 6;
      int ke = idx & 63;
      ta[cc] = *(const short8*)(hsb + (size_t)(m0 + row) * NH + k0 + ke);
      tb[cc] = *(const short8*)(wb + (size_t)(n0 + row) * NH + k0 + ke);
    }
    __syncthreads();
#pragma unroll
    for (int cc = 0; cc < 4; ++cc) {
      int idx = cc * 2048 + tid * 8;
      int row = idx >> 6;
      int ke = (idx & 63) ^ ((row & 7) << 3);
      *(short8*)(As + row * 64 + ke) = ta[cc];
      *(short8*)(Bs + row * 64 + ke) = tb[cc];
    }
    __syncthreads();
#pragma unroll
    for (int kk = 0; kk < 64; kk += 32) {
      short8 a[4], b[4];
#pragma unroll
      for (int mi = 0; mi < 4; ++mi) {
        int row = wr * 64 + mi * 16 + l15;
        a[mi] = *(const short8*)(As + row * 64 + ((kk + kl) ^ ((row & 7) << 3)));
      }
#pragma unroll
      for (int ni = 0; ni < 4; ++ni) {
        int row = wc * 64 + ni * 16 + l15;
        b[ni] = *(const short8*)(Bs + row * 64 + ((kk + kl) ^ ((row & 7) << 3)));
      }
#pragma unroll
      for (int mi = 0; mi < 4; ++mi)
#pragma unroll
        for (int ni = 0; ni < 4; ++ni)
          acc[mi][ni] = mfma16(a[mi], b[ni], acc[mi][ni]);
    }
  }

  // epilogue: per-wave LDS transpose -> f32x4 coalesced stores
  f32x4 bo4 = *(const f32x4*)(bout + n0 + wc * 64 + l15 * 4);
#pragma unroll
  for (int mi = 0; mi < 4; ++mi) {
    __syncthreads();
#pragma unroll
    for (int ni = 0; ni < 4; ++ni)
#pragma unroll
      for (int r = 0; r < 4; ++r)
        cst[w][(lane >> 4) * 4 + r][ni * 16 + l15] = acc[mi][ni][r];
    __syncthreads();
#pragma unroll
    for (int p = 0; p < 4; ++p) {
      int row16 = p * 4 + (lane >> 4);
      int m = m0 + wr * 64 + mi * 16 + row16;
      f32x4 v = *(const f32x4*)&cst[w][row16][l15 * 4];
#pragma unroll
      for (int u = 0; u < 4; ++u) v[u] += bo4[u];
      if (m < NT * NB) {
        int t = m >> 6, b = m & 63;
        *(f32x4*)(out + (size_t)b * (NT * NV) + (size_t)t * NV + n0 + wc * 64 + l15 * 4) = v;
      }
    }
  }
}

extern "C" void kernel_launch(void* const* d_in, const int* in_sizes, int n_in,
                              void* d_out, int out_size, void* d_ws, size_t ws_size,
                              hipStream_t stream) {
  const float* enc  = (const float*)d_in[0];
  const int*   cap  = (const int*)d_in[1];
  const float* emb  = (const float*)d_in[2];
  const float* Wih  = (const float*)d_in[3];
  const float* Whh  = (const float*)d_in[4];
  const float* bih  = (const float*)d_in[5];
  const float* bhh  = (const float*)d_in[6];
  const float* Wh   = (const float*)d_in[7];
  const float* bh   = (const float*)d_in[8];
  const float* Wc   = (const float*)d_in[9];
  const float* bc   = (const float*)d_in[10];
  const float* Wout = (const float*)d_in[11];
  const float* bout = (const float*)d_in[12];
  float* out = (float*)d_out;

  // workspace layout — 72,351,744 B total (proven footprint)
  char* ws = (char*)d_ws;
  constexpr size_t HA_HI = 0;                                  // 65,536
  constexpr size_t HA_LO = HA_HI + 65536;
  constexpr size_t HB_HI = HA_LO + 65536;                      // c0 f32 overlay
  constexpr size_t HB_LO = HB_HI + 65536;
  constexpr size_t HSB_OFF = HB_LO + 65536;
  constexpr size_t WB_OFF  = HSB_OFF + (size_t)4096 * NH * 2;
  constexpr size_t WP_OFF  = WB_OFF + (size_t)NV * NH * 2;
  constexpr size_t XP_OFF  = WP_OFF + (size_t)NG * NH * 2;
  unsigned short* hAhi = (unsigned short*)(ws + HA_HI);
  unsigned short* hAlo = (unsigned short*)(ws + HA_LO);
  unsigned short* hBhi = (unsigned short*)(ws + HB_HI);
  unsigned short* hBlo = (unsigned short*)(ws + HB_LO);
  float* c0f = (float*)(ws + HB_HI);                           // 128KB overlay
  unsigned short* hsb = (unsigned short*)(ws + HSB_OFF);
  unsigned short* wb  = (unsigned short*)(ws + WB_OFF);
  unsigned short* wp  = (unsigned short*)(ws + WP_OFF);
  float* xp = (float*)(ws + XP_OFF);
  int* syncc = (int*)(ws + HSB_OFF + (size_t)(NT * NB) * NH * 2);  // hsb pad

  k_prep<<<1024, 256, 0, stream>>>(Wout, wb, hsb);   // also zeroes counters
  k_prep2<<<256, 256, 0, stream>>>(Whh, wp);
  k_init<<<NB, 256, 0, stream>>>(enc, Wh, bh, Wc, bc, c0f, hAhi, hAlo);

  dim3 g2(NT, NG / 64);
  k_xp<<<g2, 256, 0, stream>>>(cap, emb, Wih, bih, bhh, xp);

  k_steps_p<<<GQ * GS, 512, 0, stream>>>(xp, wp, hAhi, hAlo, hBhi, hBlo, c0f, hsb, syncc);

  dim3 g4(32, NV / 128);
  k_logits_m<<<g4, 256, 0, stream>>>(hsb, wb, bout, out);
}